// Round 2
// baseline (921.249 us; speedup 1.0000x reference)
//
#include <hip/hip_runtime.h>
#include <hip/hip_bf16.h>
#include <stdint.h>

#define D_IN 256
#define D_H  97
#define TS   98      // padded row stride (floats) for t/h buffers; col 97 is a zero pad
#define WPAD 128     // padded weight column count

// ---------- helpers ----------
__device__ __forceinline__ int load_idx(const void* p, int is64, long long pos) {
  if (is64) return (int)(((const long long*)p)[pos]);
  return ((const int*)p)[pos];
}

// Decide whether edge_index arrived as int64 (odd 32-bit words all zero) or int32.
__global__ void detect_kernel(const void* ei, long long E, int* flag) {
  const int* p32 = (const int*)ei;
  long long stride = E / 1024; if (stride < 1) stride = 1;
  int tid = threadIdx.x;
  int bad = 0;
  for (int s = 0; s < 4; ++s) {
    long long k = ((long long)tid * 4 + s) * stride;
    if (k < E) {
      if (p32[2 * k + 1] != 0) bad = 1;   // stay within first E int64 slots: in-bounds for both layouts
    }
  }
  __shared__ int sh_bad;
  if (tid == 0) sh_bad = 0;
  __syncthreads();
  if (bad) atomicOr(&sh_bad, 1);
  __syncthreads();
  if (tid == 0) *flag = sh_bad ? 0 : 1;   // 1 => int64
}

__global__ void count_kernel(const void* ei, const int* __restrict__ flag,
                             int* __restrict__ cnt, long long E) {
  long long e = (long long)blockIdx.x * blockDim.x + threadIdx.x;
  if (e >= E) return;
  int f = *flag;
  int d = load_idx(ei, f, E + e);
  atomicAdd(&cnt[d], 1);
}

__global__ void dinv_kernel(const int* __restrict__ cnt, float* __restrict__ dinv, int N) {
  int i = blockIdx.x * blockDim.x + threadIdx.x;
  if (i >= N) return;
  dinv[i] = rsqrtf((float)(cnt[i] + 1));   // +1 self-loop; deg >= 1 always
}

// ---------- exclusive scan over cnt -> row_start (3 phases) ----------
__global__ void scan_a(const int* __restrict__ cnt, int* __restrict__ bsum, int N) {
  int b = blockIdx.x, tid = threadIdx.x;
  int lane = tid & 63, wid = tid >> 6;
  int base = b * 1024 + tid * 4;
  int v0 = (base + 0 < N) ? cnt[base + 0] : 0;
  int v1 = (base + 1 < N) ? cnt[base + 1] : 0;
  int v2 = (base + 2 < N) ? cnt[base + 2] : 0;
  int v3 = (base + 3 < N) ? cnt[base + 3] : 0;
  int t = v0 + v1 + v2 + v3;
  #pragma unroll
  for (int off = 32; off > 0; off >>= 1) t += __shfl_down(t, off, 64);
  __shared__ int sh[4];
  if (lane == 0) sh[wid] = t;
  __syncthreads();
  if (tid == 0) bsum[b] = sh[0] + sh[1] + sh[2] + sh[3];
}

__global__ void scan_b(int* __restrict__ bsum, int NB) {
  __shared__ int sh[1024];
  int tid = threadIdx.x;
  int v = (tid < NB) ? bsum[tid] : 0;
  sh[tid] = v;
  __syncthreads();
  for (int off = 1; off < 1024; off <<= 1) {
    int a = (tid >= off) ? sh[tid - off] : 0;
    __syncthreads();
    sh[tid] += a;
    __syncthreads();
  }
  if (tid < NB) bsum[tid] = sh[tid] - v;   // exclusive block offsets
}

__global__ void scan_c(const int* __restrict__ cnt, const int* __restrict__ bsum,
                       int* __restrict__ row_start, int* __restrict__ cursor,
                       int N, long long E_total) {
  int b = blockIdx.x, tid = threadIdx.x;
  int lane = tid & 63, wid = tid >> 6;
  int base = b * 1024 + tid * 4;
  int v0 = (base + 0 < N) ? cnt[base + 0] : 0;
  int v1 = (base + 1 < N) ? cnt[base + 1] : 0;
  int v2 = (base + 2 < N) ? cnt[base + 2] : 0;
  int v3 = (base + 3 < N) ? cnt[base + 3] : 0;
  int tsum = v0 + v1 + v2 + v3;
  int incl = tsum;
  #pragma unroll
  for (int off = 1; off < 64; off <<= 1) {
    int n = __shfl_up(incl, off, 64);
    if (lane >= off) incl += n;
  }
  __shared__ int wsum[4];
  if (lane == 63) wsum[wid] = incl;
  __syncthreads();
  int woff = 0;
  for (int k = 0; k < wid; ++k) woff += wsum[k];
  int excl = woff + incl - tsum + bsum[b];
  if (base + 0 < N) { row_start[base + 0] = excl;                cursor[base + 0] = excl; }
  if (base + 1 < N) { row_start[base + 1] = excl + v0;           cursor[base + 1] = excl + v0; }
  if (base + 2 < N) { row_start[base + 2] = excl + v0 + v1;      cursor[base + 2] = excl + v0 + v1; }
  if (base + 3 < N) { row_start[base + 3] = excl + v0 + v1 + v2; cursor[base + 3] = excl + v0 + v1 + v2; }
  if (b == 0 && tid == 0) row_start[N] = (int)E_total;
}

__global__ void fill_kernel(const void* ei, const int* __restrict__ flag,
                            const float* __restrict__ dinv, int* __restrict__ cursor,
                            int* __restrict__ csr_src, float* __restrict__ csr_w, long long E) {
  long long e = (long long)blockIdx.x * blockDim.x + threadIdx.x;
  if (e >= E) return;
  int f = *flag;
  int s = load_idx(ei, f, e);
  int d = load_idx(ei, f, E + e);
  int pos = atomicAdd(&cursor[d], 1);
  csr_src[pos] = s;
  csr_w[pos] = dinv[s] * dinv[d];
}

// ---------- pad weights/biases into WPAD-wide zero-padded buffers ----------
__global__ void prep_kernel(const float* __restrict__ W1, const float* __restrict__ b1,
                            const float* __restrict__ W2, const float* __restrict__ b2,
                            float* __restrict__ W1p, float* __restrict__ W2p,
                            float* __restrict__ b1p, float* __restrict__ b2p) {
  int idx = blockIdx.x * blockDim.x + threadIdx.x;
  const int n1 = 256 * WPAD, n2 = 112 * WPAD;
  if (idx < n1) {
    int k = idx / WPAD, c = idx % WPAD;
    W1p[idx] = (c < D_H) ? W1[k * D_H + c] : 0.0f;
  } else if (idx < n1 + n2) {
    int j = idx - n1; int k = j / WPAD, c = j % WPAD;
    W2p[j] = (k < D_H && c < D_H) ? W2[k * D_H + c] : 0.0f;
  } else if (idx < n1 + n2 + TS) {
    int c = idx - (n1 + n2);
    b1p[c] = (c < D_H) ? b1[c] : 0.0f;
  } else if (idx < n1 + n2 + 2 * TS) {
    int c = idx - (n1 + n2 + TS);
    b2p[c] = (c < D_H) ? b2[c] : 0.0f;
  }
}

// ---------- f32 tiled GEMM: C[N x TS(pad)] = A[N x lda] * Wp[K x WPAD] ----------
template<int K, int KEFF>
__global__ __launch_bounds__(256) void gemm_kernel(const float* __restrict__ A, int lda,
                                                   const float* __restrict__ Wp,
                                                   float* __restrict__ C, int N) {
  __shared__ float As[16][64];
  __shared__ float Ws[16][128];
  int tid = threadIdx.x;
  int row0 = blockIdx.x * 64;
  int tx = tid & 15, ty = tid >> 4;
  float acc[4][8];
  #pragma unroll
  for (int i = 0; i < 4; ++i)
    #pragma unroll
    for (int j = 0; j < 8; ++j) acc[i][j] = 0.0f;

  int ar  = tid >> 2;          // 0..63 row within tile
  int akq = (tid & 3) * 4;     // k offset 0,4,8,12
  int wc  = (tid & 31) * 4;    // 0..124
  int wk  = tid >> 5;          // 0..7

  for (int kb = 0; kb < K; kb += 16) {
    float2 a01 = make_float2(0.f, 0.f), a23 = make_float2(0.f, 0.f);
    int arow = row0 + ar;
    int k0 = kb + akq;
    if (arow < N) {
      if (k0 < KEFF)     a01 = *(const float2*)&A[(size_t)arow * lda + k0];
      if (k0 + 2 < KEFF) a23 = *(const float2*)&A[(size_t)arow * lda + k0 + 2];
    }
    As[akq + 0][ar] = a01.x; As[akq + 1][ar] = a01.y;
    As[akq + 2][ar] = a23.x; As[akq + 3][ar] = a23.y;
    *(float4*)&Ws[wk][wc]     = *(const float4*)&Wp[(size_t)(kb + wk) * WPAD + wc];
    *(float4*)&Ws[wk + 8][wc] = *(const float4*)&Wp[(size_t)(kb + wk + 8) * WPAD + wc];
    __syncthreads();
    #pragma unroll
    for (int k = 0; k < 16; ++k) {
      float4 a4 = *(const float4*)&As[k][ty * 4];
      float4 wA = *(const float4*)&Ws[k][tx * 4];
      float4 wB = *(const float4*)&Ws[k][64 + tx * 4];
      float av[4] = {a4.x, a4.y, a4.z, a4.w};
      float wv[8] = {wA.x, wA.y, wA.z, wA.w, wB.x, wB.y, wB.z, wB.w};
      #pragma unroll
      for (int i = 0; i < 4; ++i)
        #pragma unroll
        for (int j = 0; j < 8; ++j) acc[i][j] += av[i] * wv[j];
    }
    __syncthreads();
  }
  #pragma unroll
  for (int i = 0; i < 4; ++i) {
    int r = row0 + ty * 4 + i;
    if (r >= N) continue;
    float* crow = C + (size_t)r * TS;
    int cA = tx * 4, cB = 64 + tx * 4;
    *(float2*)&crow[cA]     = make_float2(acc[i][0], acc[i][1]);   // cA   <= 60  < TS always
    *(float2*)&crow[cA + 2] = make_float2(acc[i][2], acc[i][3]);   // cA+2 <= 62  < TS always
    if (cB < TS)     *(float2*)&crow[cB]     = make_float2(acc[i][4], acc[i][5]);
    if (cB + 2 < TS) *(float2*)&crow[cB + 2] = make_float2(acc[i][6], acc[i][7]);
  }
}

// ---------- CSR aggregation: one wave per destination node ----------
__global__ __launch_bounds__(256) void agg_kernel(
    const float* __restrict__ t, const int* __restrict__ csr_src,
    const float* __restrict__ csr_w, const int* __restrict__ row_start,
    const float* __restrict__ dinv, const float* __restrict__ bias,
    float* __restrict__ outp, int N, int ostride, int do_relu) {
  int lane = threadIdx.x & 63;
  int node = blockIdx.x * (blockDim.x >> 6) + (threadIdx.x >> 6);
  if (node >= N || lane >= 49) return;   // 49 lanes x float2 = 98 cols (col 97 is zero pad)
  int s = row_start[node], epd = row_start[node + 1];
  float di = dinv[node];
  float2 v = ((const float2*)(t + (size_t)node * TS))[lane];
  float wself = di * di;
  float ax = wself * v.x, ay = wself * v.y;
  int e = s;
  for (; e + 4 <= epd; e += 4) {
    int j0 = csr_src[e], j1 = csr_src[e + 1], j2 = csr_src[e + 2], j3 = csr_src[e + 3];
    float w0 = csr_w[e], w1 = csr_w[e + 1], w2 = csr_w[e + 2], w3 = csr_w[e + 3];
    float2 u0 = ((const float2*)(t + (size_t)j0 * TS))[lane];
    float2 u1 = ((const float2*)(t + (size_t)j1 * TS))[lane];
    float2 u2 = ((const float2*)(t + (size_t)j2 * TS))[lane];
    float2 u3 = ((const float2*)(t + (size_t)j3 * TS))[lane];
    ax += w0 * u0.x; ay += w0 * u0.y;
    ax += w1 * u1.x; ay += w1 * u1.y;
    ax += w2 * u2.x; ay += w2 * u2.y;
    ax += w3 * u3.x; ay += w3 * u3.y;
  }
  for (; e < epd; ++e) {
    int j = csr_src[e]; float w = csr_w[e];
    float2 u = ((const float2*)(t + (size_t)j * TS))[lane];
    ax += w * u.x; ay += w * u.y;
  }
  int c0 = 2 * lane, c1 = 2 * lane + 1;
  ax += bias[c0]; ay += bias[c1];
  if (do_relu) { ax = fmaxf(ax, 0.f); ay = fmaxf(ay, 0.f); }
  if (ostride == TS) {
    *(float2*)(outp + (size_t)node * TS + c0) = make_float2(ax, ay);
  } else {
    float* o = outp + (size_t)node * ostride;
    if (c0 < D_H) o[c0] = ax;
    if (c1 < D_H) o[c1] = ay;
  }
}

// ---------- launch ----------
extern "C" void kernel_launch(void* const* d_in, const int* in_sizes, int n_in,
                              void* d_out, int out_size, void* d_ws, size_t ws_size,
                              hipStream_t stream) {
  const float* x  = (const float*)d_in[0];
  const void*  ei = d_in[1];
  const float* W1 = (const float*)d_in[2];
  const float* b1 = (const float*)d_in[3];
  const float* W2 = (const float*)d_in[4];
  const float* b2 = (const float*)d_in[5];
  int N = in_sizes[0] / D_IN;
  long long E = (long long)in_sizes[1] / 2;

  char* base = (char*)d_ws;
  size_t off = 0;
  auto alloc = [&](size_t bytes) -> void* {
    void* p = base + off;
    off = (off + bytes + 255) & ~(size_t)255;
    return p;
  };
  int*   flag      = (int*)alloc(4);
  int*   cnt       = (int*)alloc((size_t)N * 4);
  float* dinv      = (float*)alloc((size_t)N * 4);
  int*   row_start = (int*)alloc((size_t)(N + 1) * 4);
  int*   cursor    = (int*)alloc((size_t)N * 4);
  int*   bsum      = (int*)alloc(4096);
  int*   csr_src   = (int*)alloc((size_t)E * 4);
  float* csr_w     = (float*)alloc((size_t)E * 4);
  float* W1p       = (float*)alloc((size_t)256 * WPAD * 4);
  float* W2p       = (float*)alloc((size_t)112 * WPAD * 4);
  float* b1p       = (float*)alloc(TS * 4);
  float* b2p       = (float*)alloc(TS * 4);
  float* t1        = (float*)alloc(((size_t)N * TS + 64) * 4);
  float* h1        = (float*)alloc(((size_t)N * TS + 64) * 4);

  hipMemsetAsync(cnt, 0, (size_t)N * 4, stream);
  detect_kernel<<<1, 256, 0, stream>>>(ei, E, flag);
  count_kernel<<<(int)((E + 255) / 256), 256, 0, stream>>>(ei, flag, cnt, E);
  dinv_kernel<<<(N + 255) / 256, 256, 0, stream>>>(cnt, dinv, N);
  int NB = (N + 1023) / 1024;
  scan_a<<<NB, 256, 0, stream>>>(cnt, bsum, N);
  scan_b<<<1, 1024, 0, stream>>>(bsum, NB);
  scan_c<<<NB, 256, 0, stream>>>(cnt, bsum, row_start, cursor, N, E);
  fill_kernel<<<(int)((E + 255) / 256), 256, 0, stream>>>(ei, flag, dinv, cursor, csr_src, csr_w, E);
  prep_kernel<<<(256 * WPAD + 112 * WPAD + 2 * TS + 255) / 256, 256, 0, stream>>>(
      W1, b1, W2, b2, W1p, W2p, b1p, b2p);
  gemm_kernel<256, 256><<<(N + 63) / 64, 256, 0, stream>>>(x, D_IN, W1p, t1, N);
  agg_kernel<<<(N + 3) / 4, 256, 0, stream>>>(t1, csr_src, csr_w, row_start, dinv, b1p, h1, N, TS, 1);
  gemm_kernel<112, 98><<<(N + 63) / 64, 256, 0, stream>>>(h1, TS, W2p, t1, N);
  agg_kernel<<<(N + 3) / 4, 256, 0, stream>>>(t1, csr_src, csr_w, row_start, dinv, b2p,
                                              (float*)d_out, N, D_H, 0);
}